// Round 7
// baseline (338.156 us; speedup 1.0000x reference)
//
#include <hip/hip_runtime.h>
#include <hip/hip_bf16.h>
#include <math.h>

#define N_NODES 4096
#define F_IN0   512
#define HEADS   4
#define O_DIM   256
#define HO      1024   // HEADS*O_DIM
#define LRELU_A 0.2f
#define MAXE    192
#define LOG2E   1.44269504088896f

typedef __bf16 bf16_t;
typedef bf16_t bf16x8 __attribute__((ext_vector_type(8)));
typedef float f32x4 __attribute__((ext_vector_type(4)));
typedef unsigned short u16x8 __attribute__((ext_vector_type(8)));

__device__ __forceinline__ unsigned short f2b(float f) {
    __hip_bfloat16 t = __float2bfloat16(f);
    return __builtin_bit_cast(unsigned short, t);
}
__device__ __forceinline__ float b2f(unsigned short u) {
    unsigned int v = ((unsigned int)u) << 16;
    return __builtin_bit_cast(float, v);
}
__device__ __forceinline__ float fexp(float x) {          // e^x, hw exp2
    return __builtin_amdgcn_exp2f(x * LOG2E);
}
__device__ __forceinline__ float fsigmoid(float x) {      // 1/(1+e^-x)
    return __builtin_amdgcn_rcpf(1.f + __builtin_amdgcn_exp2f(-x * LOG2E));
}

#define GLOAD_LDS(g, l) \
    __builtin_amdgcn_global_load_lds((const __attribute__((address_space(1))) unsigned int*)(g), \
                                     (__attribute__((address_space(3))) unsigned int*)(l), 16, 0, 0)

// ---------------- fused prep: f2bf(x) | W0^T | W1^T | edges + zero score bufs
__device__ __forceinline__ void transpose_tile(const float* __restrict__ W,
                                               unsigned short* __restrict__ Wt,
                                               int K, int O, int kt, int ot, int h,
                                               float (*t)[33], int tid) {
    const float* Wh = W + (size_t)h * K * O;
    unsigned short* Wth = Wt + (size_t)h * K * O;
    const int k0 = kt * 32, o0 = ot * 32;
    const int tx = tid & 31, ty = tid >> 5;   // 32 x 8
    for (int r = ty; r < 32; r += 8) t[r][tx] = Wh[(size_t)(k0 + r) * O + o0 + tx];
    __syncthreads();
    for (int r = ty; r < 32; r += 8)
        Wth[(size_t)(o0 + r) * K + k0 + tx] = f2b(t[tx][r]);
}

__global__ __launch_bounds__(256) void prep_k(const float* __restrict__ x,
                                              const float* __restrict__ W0,
                                              const float* __restrict__ W1,
                                              const float* __restrict__ adj,
                                              unsigned short* __restrict__ xb,
                                              unsigned short* __restrict__ wt0,
                                              unsigned short* __restrict__ wt1,
                                              int* __restrict__ ecnt,
                                              int* __restrict__ eidx,
                                              float* __restrict__ szero) {
    __shared__ float t[32][33];
    const int b = blockIdx.x;
    const int tid = threadIdx.x;
    if (b < 2048) {                       // x -> bf16 (524288 float4 groups)
        int i = b * 256 + tid;
        float4 v = ((const float4*)x)[i];
        ushort4 o;
        o.x = f2b(v.x); o.y = f2b(v.y); o.z = f2b(v.z); o.w = f2b(v.w);
        ((ushort4*)xb)[i] = o;
    } else if (b < 2560) {                // W0 transpose: 16 kt x 8 ot x 4 h
        int b2 = b - 2048;
        transpose_tile(W0, wt0, F_IN0, O_DIM, (b2 & 15), ((b2 >> 4) & 7), b2 >> 7, t, tid);
    } else if (b < 3584) {                // W1 transpose: 32 kt x 8 ot x 4 h
        int b2 = b - 2560;
        transpose_tile(W1, wt1, HO, O_DIM, (b2 & 31), ((b2 >> 5) & 7), b2 >> 8, t, tid);
    } else {                              // edges: one wave per adjacency row
        const int w    = tid >> 6;
        const int lane = tid & 63;
        const int n    = (b - 3584) * 4 + w;
        const float* adjr = adj + (size_t)n * N_NODES;
        float4 a4[16];
#pragma unroll
        for (int it = 0; it < 16; ++it)
            a4[it] = *(const float4*)&adjr[lane * 4 + it * 256];
        unsigned long long mask = 0;
#pragma unroll
        for (int it = 0; it < 16; ++it) {
            if (a4[it].x > 0.f) mask |= 1ull << (it * 4 + 0);
            if (a4[it].y > 0.f) mask |= 1ull << (it * 4 + 1);
            if (a4[it].z > 0.f) mask |= 1ull << (it * 4 + 2);
            if (a4[it].w > 0.f) mask |= 1ull << (it * 4 + 3);
        }
        const int ec = __popcll(mask);
        int sc = ec;                          // wave inclusive scan
#pragma unroll
        for (int off = 1; off < 64; off <<= 1) {
            int u = __shfl_up(sc, off, 64);
            if (lane >= off) sc += u;
        }
        int base = sc - ec;
        unsigned long long mm = mask;
        while (mm) {
            const int q = __builtin_ctzll(mm);
            mm &= mm - 1;
            const int m = lane * 4 + ((q >> 2) << 8) + (q & 3);
            eidx[(size_t)n * MAXE + base] = m;
            ++base;
        }
        if (lane == 63) ecnt[n] = sc;
        // zero the 4 score accumulators (L0 self/neigh, L1 self/neigh) for this row
        if (lane < 16) szero[(size_t)(lane >> 2) * N_NODES * HEADS + n * HEADS + (lane & 3)] = 0.f;
    }
}

// ---------------- MFMA NT GEMM 64x64 + dbuf + fused attention-score epilogue
// scores: s_self[n][z] += sum_o C[n][o]*a_s[z][o]; accumulated via atomics over col-tiles.
__global__ __launch_bounds__(256) void mfma_nt(const bf16_t* __restrict__ A,
                                               const bf16_t* __restrict__ B,
                                               unsigned short* __restrict__ Cv,
                                               const float* __restrict__ a_s,
                                               const float* __restrict__ a_n,
                                               float* __restrict__ s_self,
                                               float* __restrict__ s_neigh,
                                               int K, int ldc,
                                               unsigned long long bStride,
                                               unsigned long long cStride) {
    B += blockIdx.z * bStride;
    const size_t zoff = (size_t)blockIdx.z * cStride;
    __shared__ bf16_t sAB[2][2][64 * 32];
    const int tid  = threadIdx.x;
    const int lane = tid & 63;
    const int wave = tid >> 6;
    const int wr = (wave >> 1) * 32;
    const int wc = (wave & 1) * 32;
    const int rowBase = blockIdx.x * 64;
    const int colBase = blockIdx.y * 64;
    const int l15  = lane & 15;
    const int quad = lane >> 4;

    const int sm = tid & 63;
    const int sc = tid >> 6;
    const bf16_t* aRow = A + (size_t)(rowBase + sm) * K + sc * 8;
    const bf16_t* bRow = B + (size_t)(colBase + sm) * K + sc * 8;

    f32x4 acc[2][2] = {};

    GLOAD_LDS(aRow, &sAB[0][0][tid * 8]);
    GLOAD_LDS(bRow, &sAB[0][1][tid * 8]);
    __syncthreads();

    int cur = 0;
    for (int k0 = 0; k0 < K; k0 += 32) {
        if (k0 + 32 < K) {
            GLOAD_LDS(aRow + k0 + 32, &sAB[cur ^ 1][0][tid * 8]);
            GLOAD_LDS(bRow + k0 + 32, &sAB[cur ^ 1][1][tid * 8]);
        }
        bf16x8 af[2], bfr[2];
#pragma unroll
        for (int i = 0; i < 2; ++i) {
            af[i]  = *(bf16x8*)&sAB[cur][0][(quad * 64 + wr + i * 16 + l15) * 8];
            bfr[i] = *(bf16x8*)&sAB[cur][1][(quad * 64 + wc + i * 16 + l15) * 8];
        }
#pragma unroll
        for (int i = 0; i < 2; ++i)
#pragma unroll
            for (int j = 0; j < 2; ++j)
                acc[i][j] = __builtin_amdgcn_mfma_f32_16x16x32_bf16(af[i], bfr[j], acc[i][j], 0, 0, 0);
        __syncthreads();
        cur ^= 1;
    }

    const int orow = rowBase + wr + quad * 4;
    const int ocol = colBase + wc + l15;
#pragma unroll
    for (int i = 0; i < 2; ++i)
#pragma unroll
        for (int j = 0; j < 2; ++j)
#pragma unroll
            for (int r = 0; r < 4; ++r)
                Cv[zoff + (size_t)(orow + i * 16 + r) * ldc + ocol + j * 16] = f2b(acc[i][j][r]);

    // ---- fused scores epilogue
    float ps[2][4] = {}, pn[2][4] = {};
#pragma unroll
    for (int j = 0; j < 2; ++j) {
        const float av = a_s[blockIdx.z * O_DIM + ocol + j * 16];
        const float nv = a_n[blockIdx.z * O_DIM + ocol + j * 16];
#pragma unroll
        for (int i = 0; i < 2; ++i)
#pragma unroll
            for (int r = 0; r < 4; ++r) {
                ps[i][r] += acc[i][j][r] * av;
                pn[i][r] += acc[i][j][r] * nv;
            }
    }
#pragma unroll
    for (int off = 1; off < 16; off <<= 1)
#pragma unroll
        for (int i = 0; i < 2; ++i)
#pragma unroll
            for (int r = 0; r < 4; ++r) {
                ps[i][r] += __shfl_xor(ps[i][r], off, 64);
                pn[i][r] += __shfl_xor(pn[i][r], off, 64);
            }
    if (l15 == 0) {
#pragma unroll
        for (int i = 0; i < 2; ++i)
#pragma unroll
            for (int r = 0; r < 4; ++r) {
                const int row = orow + i * 16 + r;
                atomicAdd(&s_self[row * HEADS + blockIdx.z],  ps[i][r]);
                atomicAdd(&s_neigh[row * HEADS + blockIdx.z], pn[i][r]);
            }
    }
}

// ---------------- decode: out = sigmoid(Z Z^T), dbuf staging + coalesced epilogue
#define EP_STRIDE 132
__global__ __launch_bounds__(256) void decode_k(const bf16_t* __restrict__ Z,
                                                float* __restrict__ out) {
    __shared__ float smem_f[8192];                      // 32 KB: 2 x (A 8KB + B 8KB)
    bf16_t* base = (bf16_t*)smem_f;
    float*  sE = smem_f;

    const int tid  = threadIdx.x;
    const int lane = tid & 63;
    const int wave = tid >> 6;
    const int wr = (wave >> 1) * 64;
    const int wc = (wave & 1) * 64;
    const int rowBase = blockIdx.x * 128;
    const int colBase = blockIdx.y * 128;
    const int l15  = lane & 15;
    const int quad = lane >> 4;

    const int sm = tid & 127;
    const int sc = tid >> 7;
    const bf16_t* aRow = Z + (size_t)(rowBase + sm) * O_DIM + sc * 8;
    const bf16_t* bRow = Z + (size_t)(colBase + sm) * O_DIM + sc * 8;

    f32x4 acc[4][4] = {};

    GLOAD_LDS(aRow,      base + tid * 8);
    GLOAD_LDS(aRow + 16, base + (256 + tid) * 8);
    GLOAD_LDS(bRow,      base + 4096 + tid * 8);
    GLOAD_LDS(bRow + 16, base + 4096 + (256 + tid) * 8);
    __syncthreads();

    int cur = 0;
    for (int k0 = 0; k0 < O_DIM; k0 += 32) {
        if (k0 + 32 < O_DIM) {
            bf16_t* nA = base + (cur ^ 1) * 8192;
            GLOAD_LDS(aRow + k0 + 32, nA + tid * 8);
            GLOAD_LDS(aRow + k0 + 48, nA + (256 + tid) * 8);
            GLOAD_LDS(bRow + k0 + 32, nA + 4096 + tid * 8);
            GLOAD_LDS(bRow + k0 + 48, nA + 4096 + (256 + tid) * 8);
        }
        bf16_t* sA = base + cur * 8192;
        bf16_t* sB = sA + 4096;
        bf16x8 af[4], bfr[4];
#pragma unroll
        for (int i = 0; i < 4; ++i) {
            af[i]  = *(bf16x8*)&sA[(quad * 128 + wr + i * 16 + l15) * 8];
            bfr[i] = *(bf16x8*)&sB[(quad * 128 + wc + i * 16 + l15) * 8];
        }
#pragma unroll
        for (int i = 0; i < 4; ++i)
#pragma unroll
            for (int j = 0; j < 4; ++j)
                acc[i][j] = __builtin_amdgcn_mfma_f32_16x16x32_bf16(af[i], bfr[j], acc[i][j], 0, 0, 0);
        __syncthreads();
        cur ^= 1;
    }

    const int lrBase = (wave >> 1) * 16;
    for (int i = 0; i < 4; ++i) {
#pragma unroll
        for (int j = 0; j < 4; ++j)
#pragma unroll
            for (int r = 0; r < 4; ++r)
                sE[(lrBase + quad * 4 + r) * EP_STRIDE + wc + j * 16 + l15] = acc[i][j][r];
        __syncthreads();
#pragma unroll
        for (int p = 0; p < 4; ++p) {
            const int idx4 = p * 256 + tid;
            const int lr = idx4 >> 5;
            const int c4 = idx4 & 31;
            f32x4 v = *(f32x4*)&sE[lr * EP_STRIDE + c4 * 4];
            f32x4 o;
            o[0] = fsigmoid(v[0]); o[1] = fsigmoid(v[1]);
            o[2] = fsigmoid(v[2]); o[3] = fsigmoid(v[3]);
            const int grow = rowBase + (lr >> 4) * 64 + i * 16 + (lr & 15);
            *(f32x4*)&out[(size_t)grow * N_NODES + colBase + c4 * 4] = o;
        }
        __syncthreads();
    }
}

// ---------------- sparse attention (+ fused L2-norm on layer 1)
__global__ __launch_bounds__(256) void attn_k(const unsigned short* __restrict__ hb,
                                              const int* __restrict__ ecnt,
                                              const int* __restrict__ eidx,
                                              const float* __restrict__ Mm,
                                              const float* __restrict__ s_self4,
                                              const float* __restrict__ s_neigh4,
                                              unsigned short* __restrict__ out0,
                                              float* __restrict__ out1,
                                              unsigned short* __restrict__ zb,
                                              int layer) {
    const int n = blockIdx.x;
    const int tid = threadIdx.x;
    __shared__ int midx[MAXE];
    __shared__ float ev[MAXE][HEADS];
    __shared__ float red2[2][HO];
    __shared__ float ws2[4];
    const int c = ecnt[n];

    // phase 1: per-edge scores (leaky relu); M gathered directly
    if (tid < c) {
        const int m = eidx[(size_t)n * MAXE + tid];
        const float Mv = Mm[((size_t)n << 12) + m];
        midx[tid] = m;
        const float4 ss = *(const float4*)&s_self4[n * HEADS];
        const float4 sn = *(const float4*)&s_neigh4[m * HEADS];
        float e0 = (ss.x + sn.x) * Mv, e1 = (ss.y + sn.y) * Mv;
        float e2 = (ss.z + sn.z) * Mv, e3 = (ss.w + sn.w) * Mv;
        ev[tid][0] = e0 > 0.f ? e0 : LRELU_A * e0;
        ev[tid][1] = e1 > 0.f ? e1 : LRELU_A * e1;
        ev[tid][2] = e2 > 0.f ? e2 : LRELU_A * e2;
        ev[tid][3] = e3 > 0.f ? e3 : LRELU_A * e3;
    }
    __syncthreads();

    // phase 2: wave w = softmax over head w
    {
        const int w = tid >> 6, lane = tid & 63;
        float mx = -1e30f;
        for (int k = lane; k < c; k += 64) mx = fmaxf(mx, ev[k][w]);
        for (int off = 32; off; off >>= 1) mx = fmaxf(mx, __shfl_xor(mx, off, 64));
        float s = 0.f;
        for (int k = lane; k < c; k += 64) {
            float p = fexp(ev[k][w] - mx);
            ev[k][w] = p;
            s += p;
        }
        for (int off = 32; off; off >>= 1) s += __shfl_xor(s, off, 64);
        float inv = __builtin_amdgcn_rcpf(s);
        for (int k = lane; k < c; k += 64) ev[k][w] *= inv;
    }
    __syncthreads();

    // phase 3: gather-aggregate; halves process even/odd edges
    const int half = tid >> 7;
    const int t    = tid & 127;
    const int hh   = t >> 5;
    float acc[8] = {};
#pragma unroll 2
    for (int k = half; k < c; k += 2) {
        const int m = midx[k];
        const float w = ev[k][hh];
        const u16x8 hv = *(const u16x8*)&hb[(size_t)m * HO + t * 8];
#pragma unroll
        for (int j = 0; j < 8; ++j) acc[j] += w * b2f(hv[j]);
    }
#pragma unroll
    for (int j = 0; j < 8; ++j) red2[half][t * 8 + j] = acc[j];
    __syncthreads();

    if (layer == 0) {
        const int o = tid * 4;
        ushort4 ov;
        float v0 = red2[0][o + 0] + red2[1][o + 0];
        float v1 = red2[0][o + 1] + red2[1][o + 1];
        float v2 = red2[0][o + 2] + red2[1][o + 2];
        float v3 = red2[0][o + 3] + red2[1][o + 3];
        ov.x = f2b(v0 > 0.f ? v0 : fexp(v0) - 1.f);
        ov.y = f2b(v1 > 0.f ? v1 : fexp(v1) - 1.f);
        ov.z = f2b(v2 > 0.f ? v2 : fexp(v2) - 1.f);
        ov.w = f2b(v3 > 0.f ? v3 : fexp(v3) - 1.f);
        *(ushort4*)&out0[(size_t)n * HO + o] = ov;
    } else {
        // head-mean + fused row L2 normalize
        const int o = tid;
        float v = 0.f;
#pragma unroll
        for (int h = 0; h < HEADS; ++h)
            v += red2[0][h * O_DIM + o] + red2[1][h * O_DIM + o];
        v *= 0.25f;
        float p = v * v;
        for (int off = 32; off; off >>= 1) p += __shfl_down(p, off, 64);
        if ((tid & 63) == 0) ws2[tid >> 6] = p;
        __syncthreads();
        const float ssq = ws2[0] + ws2[1] + ws2[2] + ws2[3];
        const float denom = fmaxf(sqrtf(ssq), 1e-12f);
        const float zn = v / denom;
        out1[(size_t)n * O_DIM + o] = zn;
        zb[(size_t)n * O_DIM + o]   = f2b(zn);
    }
}

extern "C" void kernel_launch(void* const* d_in, const int* in_sizes, int n_in,
                              void* d_out, int out_size, void* d_ws, size_t ws_size,
                              hipStream_t stream) {
    const float* x   = (const float*)d_in[0];
    const float* adj = (const float*)d_in[1];
    const float* Mm  = (const float*)d_in[2];
    const float* W0  = (const float*)d_in[3];
    const float* as0 = (const float*)d_in[4];
    const float* an0 = (const float*)d_in[5];
    const float* W1  = (const float*)d_in[6];
    const float* as1 = (const float*)d_in[7];
    const float* an1 = (const float*)d_in[8];
    float* out = (float*)d_out;

    unsigned short* hb    = (unsigned short*)d_ws;        // [N][HO] bf16, 8 MB
    unsigned short* hin1b = hb + (size_t)N_NODES * HO;    // [N][HO] bf16, 8 MB
    unsigned short* xb    = hin1b + (size_t)N_NODES * HO; // [N][F] bf16, 4 MB
    unsigned short* wt0   = xb + (size_t)N_NODES * F_IN0; // 1 MB
    unsigned short* wt1   = wt0 + HEADS * O_DIM * F_IN0;  // 2 MB
    unsigned short* zb    = wt1 + HEADS * O_DIM * HO;     // [N][O] bf16, 2 MB
    float* s0s = (float*)(zb + (size_t)N_NODES * O_DIM);  // 4 score bufs, 64 KB each
    float* s0n = s0s + (size_t)N_NODES * HEADS;
    float* s1s = s0n + (size_t)N_NODES * HEADS;
    float* s1n = s1s + (size_t)N_NODES * HEADS;
    int*   eidx = (int*)(s1n + (size_t)N_NODES * HEADS);
    int*   ecnt = eidx + (size_t)N_NODES * MAXE;
    float* zbuf = out + (size_t)N_NODES * N_NODES;  // z fp32 in d_out tail

    // fused prep: conversions | transposes | edges | zero score bufs (s0s..s1n contiguous)
    prep_k<<<4608, 256, 0, stream>>>(x, W0, W1, adj, xb, wt0, wt1, ecnt, eidx, s0s);

    // layer 0: GEMM + fused scores
    mfma_nt<<<dim3(64, 4, 4), 256, 0, stream>>>((const bf16_t*)xb, (const bf16_t*)wt0, hb,
                                                as0, an0, s0s, s0n,
                                                F_IN0, HO,
                                                (unsigned long long)O_DIM * F_IN0,
                                                (unsigned long long)O_DIM);
    attn_k<<<N_NODES, 256, 0, stream>>>(hb, ecnt, eidx, Mm, s0s, s0n, hin1b, nullptr, nullptr, 0);

    // layer 1: GEMM + fused scores; attn + fused norm
    mfma_nt<<<dim3(64, 4, 4), 256, 0, stream>>>((const bf16_t*)hin1b, (const bf16_t*)wt1, hb,
                                                as1, an1, s1s, s1n,
                                                HO, HO,
                                                (unsigned long long)O_DIM * HO,
                                                (unsigned long long)O_DIM);
    attn_k<<<N_NODES, 256, 0, stream>>>(hb, ecnt, eidx, Mm, s1s, s1n, nullptr, zbuf, zb, 1);

    // decode
    decode_k<<<dim3(32, 32), 256, 0, stream>>>((const bf16_t*)zb, out);
}

// Round 8
// 308.318 us; speedup vs baseline: 1.0968x; 1.0968x over previous
//
#include <hip/hip_runtime.h>
#include <hip/hip_bf16.h>
#include <math.h>

#define N_NODES 4096
#define F_IN0   512
#define HEADS   4
#define O_DIM   256
#define HO      1024   // HEADS*O_DIM
#define LRELU_A 0.2f
#define MAXE    192
#define LOG2E   1.44269504088896f

typedef __bf16 bf16_t;
typedef bf16_t bf16x8 __attribute__((ext_vector_type(8)));
typedef float f32x4 __attribute__((ext_vector_type(4)));
typedef unsigned short u16x8 __attribute__((ext_vector_type(8)));

__device__ __forceinline__ unsigned short f2b(float f) {
    __hip_bfloat16 t = __float2bfloat16(f);
    return __builtin_bit_cast(unsigned short, t);
}
__device__ __forceinline__ float b2f(unsigned short u) {
    unsigned int v = ((unsigned int)u) << 16;
    return __builtin_bit_cast(float, v);
}
__device__ __forceinline__ float fexp(float x) {          // e^x, hw exp2
    return __builtin_amdgcn_exp2f(x * LOG2E);
}
__device__ __forceinline__ float fsigmoid(float x) {      // 1/(1+e^-x)
    return __builtin_amdgcn_rcpf(1.f + __builtin_amdgcn_exp2f(-x * LOG2E));
}

#define GLOAD_LDS(g, l) \
    __builtin_amdgcn_global_load_lds((const __attribute__((address_space(1))) unsigned int*)(g), \
                                     (__attribute__((address_space(3))) unsigned int*)(l), 16, 0, 0)

// Staging swizzle: thread t covers row (t>>2), 16B chunk (t&3) of a 64-row x 64B panel.
// 4 lanes/row -> TA merges to 1 line-request/row (was 64 requests/wave at 1 lane/row).
// Global chunk is XOR'd with (row>>1)&3 so fragment ds_reads are 2-way bank-aliased (free).

// ---------------- fused prep: f2bf(x) | W0^T | W1^T | edges + zero score bufs
__device__ __forceinline__ void transpose_tile(const float* __restrict__ W,
                                               unsigned short* __restrict__ Wt,
                                               int K, int O, int kt, int ot, int h,
                                               float (*t)[33], int tid) {
    const float* Wh = W + (size_t)h * K * O;
    unsigned short* Wth = Wt + (size_t)h * K * O;
    const int k0 = kt * 32, o0 = ot * 32;
    const int tx = tid & 31, ty = tid >> 5;   // 32 x 8
    for (int r = ty; r < 32; r += 8) t[r][tx] = Wh[(size_t)(k0 + r) * O + o0 + tx];
    __syncthreads();
    for (int r = ty; r < 32; r += 8)
        Wth[(size_t)(o0 + r) * K + k0 + tx] = f2b(t[tx][r]);
}

__global__ __launch_bounds__(256) void prep_k(const float* __restrict__ x,
                                              const float* __restrict__ W0,
                                              const float* __restrict__ W1,
                                              const float* __restrict__ adj,
                                              unsigned short* __restrict__ xb,
                                              unsigned short* __restrict__ wt0,
                                              unsigned short* __restrict__ wt1,
                                              int* __restrict__ ecnt,
                                              int* __restrict__ eidx,
                                              float* __restrict__ szero) {
    __shared__ float t[32][33];
    const int b = blockIdx.x;
    const int tid = threadIdx.x;
    if (b < 2048) {                       // x -> bf16 (524288 float4 groups)
        int i = b * 256 + tid;
        float4 v = ((const float4*)x)[i];
        ushort4 o;
        o.x = f2b(v.x); o.y = f2b(v.y); o.z = f2b(v.z); o.w = f2b(v.w);
        ((ushort4*)xb)[i] = o;
    } else if (b < 2560) {                // W0 transpose: 16 kt x 8 ot x 4 h
        int b2 = b - 2048;
        transpose_tile(W0, wt0, F_IN0, O_DIM, (b2 & 15), ((b2 >> 4) & 7), b2 >> 7, t, tid);
    } else if (b < 3584) {                // W1 transpose: 32 kt x 8 ot x 4 h
        int b2 = b - 2560;
        transpose_tile(W1, wt1, HO, O_DIM, (b2 & 31), ((b2 >> 5) & 7), b2 >> 8, t, tid);
    } else {                              // edges: one wave per adjacency row
        const int w    = tid >> 6;
        const int lane = tid & 63;
        const int n    = (b - 3584) * 4 + w;
        const float* adjr = adj + (size_t)n * N_NODES;
        float4 a4[16];
#pragma unroll
        for (int it = 0; it < 16; ++it)
            a4[it] = *(const float4*)&adjr[lane * 4 + it * 256];
        unsigned long long mask = 0;
#pragma unroll
        for (int it = 0; it < 16; ++it) {
            if (a4[it].x > 0.f) mask |= 1ull << (it * 4 + 0);
            if (a4[it].y > 0.f) mask |= 1ull << (it * 4 + 1);
            if (a4[it].z > 0.f) mask |= 1ull << (it * 4 + 2);
            if (a4[it].w > 0.f) mask |= 1ull << (it * 4 + 3);
        }
        const int ec = __popcll(mask);
        int sc = ec;                          // wave inclusive scan
#pragma unroll
        for (int off = 1; off < 64; off <<= 1) {
            int u = __shfl_up(sc, off, 64);
            if (lane >= off) sc += u;
        }
        int base = sc - ec;
        unsigned long long mm = mask;
        while (mm) {
            const int q = __builtin_ctzll(mm);
            mm &= mm - 1;
            const int m = lane * 4 + ((q >> 2) << 8) + (q & 3);
            eidx[(size_t)n * MAXE + base] = m;
            ++base;
        }
        if (lane == 63) ecnt[n] = sc;
        // zero the 4 score accumulators (L0 self/neigh, L1 self/neigh) for this row
        if (lane < 16) szero[(size_t)(lane >> 2) * N_NODES * HEADS + n * HEADS + (lane & 3)] = 0.f;
    }
}

// ---------------- MFMA NT GEMM 64x64 + dbuf + merged-line staging + fused score epilogue
__global__ __launch_bounds__(256) void mfma_nt(const bf16_t* __restrict__ A,
                                               const bf16_t* __restrict__ B,
                                               unsigned short* __restrict__ Cv,
                                               const float* __restrict__ a_s,
                                               const float* __restrict__ a_n,
                                               float* __restrict__ s_self,
                                               float* __restrict__ s_neigh,
                                               int K, int ldc,
                                               unsigned long long bStride,
                                               unsigned long long cStride) {
    B += blockIdx.z * bStride;
    const size_t zoff = (size_t)blockIdx.z * cStride;
    __shared__ bf16_t sAB[2][2][64 * 32];
    const int tid  = threadIdx.x;
    const int lane = tid & 63;
    const int wave = tid >> 6;
    const int wr = (wave >> 1) * 32;
    const int wc = (wave & 1) * 32;
    const int rowBase = blockIdx.x * 64;
    const int colBase = blockIdx.y * 64;
    const int l15  = lane & 15;
    const int quad = lane >> 4;

    // staging: row = tid>>2 (4 lanes/row -> merged line requests), swizzled k-chunk
    const int sr = tid >> 2;
    const int sg = (tid & 3) ^ ((tid >> 3) & 3);
    const bf16_t* aSrc = A + (size_t)(rowBase + sr) * K + sg * 8;
    const bf16_t* bSrc = B + (size_t)(colBase + sr) * K + sg * 8;

    f32x4 acc[2][2] = {};

    GLOAD_LDS(aSrc, &sAB[0][0][tid * 8]);
    GLOAD_LDS(bSrc, &sAB[0][1][tid * 8]);
    __syncthreads();

    int cur = 0;
    for (int k0 = 0; k0 < K; k0 += 32) {
        if (k0 + 32 < K) {
            GLOAD_LDS(aSrc + k0 + 32, &sAB[cur ^ 1][0][tid * 8]);
            GLOAD_LDS(bSrc + k0 + 32, &sAB[cur ^ 1][1][tid * 8]);
        }
        bf16x8 af[2], bfr[2];
#pragma unroll
        for (int i = 0; i < 2; ++i) {
            const int ra = wr + i * 16 + l15;
            const int rb = wc + i * 16 + l15;
            af[i]  = *(bf16x8*)&sAB[cur][0][ra * 32 + ((quad ^ ((ra >> 1) & 3)) << 3)];
            bfr[i] = *(bf16x8*)&sAB[cur][1][rb * 32 + ((quad ^ ((rb >> 1) & 3)) << 3)];
        }
#pragma unroll
        for (int i = 0; i < 2; ++i)
#pragma unroll
            for (int j = 0; j < 2; ++j)
                acc[i][j] = __builtin_amdgcn_mfma_f32_16x16x32_bf16(af[i], bfr[j], acc[i][j], 0, 0, 0);
        __syncthreads();
        cur ^= 1;
    }

    const int orow = rowBase + wr + quad * 4;
    const int ocol = colBase + wc + l15;
#pragma unroll
    for (int i = 0; i < 2; ++i)
#pragma unroll
        for (int j = 0; j < 2; ++j)
#pragma unroll
            for (int r = 0; r < 4; ++r)
                Cv[zoff + (size_t)(orow + i * 16 + r) * ldc + ocol + j * 16] = f2b(acc[i][j][r]);

    // ---- fused scores epilogue
    float ps[2][4] = {}, pn[2][4] = {};
#pragma unroll
    for (int j = 0; j < 2; ++j) {
        const float av = a_s[blockIdx.z * O_DIM + ocol + j * 16];
        const float nv = a_n[blockIdx.z * O_DIM + ocol + j * 16];
#pragma unroll
        for (int i = 0; i < 2; ++i)
#pragma unroll
            for (int r = 0; r < 4; ++r) {
                ps[i][r] += acc[i][j][r] * av;
                pn[i][r] += acc[i][j][r] * nv;
            }
    }
#pragma unroll
    for (int off = 1; off < 16; off <<= 1)
#pragma unroll
        for (int i = 0; i < 2; ++i)
#pragma unroll
            for (int r = 0; r < 4; ++r) {
                ps[i][r] += __shfl_xor(ps[i][r], off, 64);
                pn[i][r] += __shfl_xor(pn[i][r], off, 64);
            }
    if (l15 == 0) {
#pragma unroll
        for (int i = 0; i < 2; ++i)
#pragma unroll
            for (int r = 0; r < 4; ++r) {
                const int row = orow + i * 16 + r;
                atomicAdd(&s_self[row * HEADS + blockIdx.z],  ps[i][r]);
                atomicAdd(&s_neigh[row * HEADS + blockIdx.z], pn[i][r]);
            }
    }
}

// ---------------- decode: out = sigmoid(Z Z^T), merged-line dbuf staging + coalesced epilogue
#define EP_STRIDE 132
__global__ __launch_bounds__(256) void decode_k(const bf16_t* __restrict__ Z,
                                                float* __restrict__ out) {
    __shared__ float smem_f[8192];                      // 32 KB: 2 x (A 8KB + B 8KB)
    bf16_t* base = (bf16_t*)smem_f;
    float*  sE = smem_f;

    const int tid  = threadIdx.x;
    const int lane = tid & 63;
    const int wave = tid >> 6;
    const int wr = (wave >> 1) * 64;
    const int wc = (wave & 1) * 64;
    const int rowBase = blockIdx.x * 128;
    const int colBase = blockIdx.y * 128;
    const int l15  = lane & 15;
    const int quad = lane >> 4;

    // staging: 4 lanes/row, swizzled k-chunk; two 64-row instrs per matrix
    const int sr = tid >> 2;
    const int sg = (tid & 3) ^ ((tid >> 3) & 3);
    const bf16_t* aSrc  = Z + (size_t)(rowBase + sr) * O_DIM + sg * 8;
    const bf16_t* aSrc2 = Z + (size_t)(rowBase + 64 + sr) * O_DIM + sg * 8;
    const bf16_t* bSrc  = Z + (size_t)(colBase + sr) * O_DIM + sg * 8;
    const bf16_t* bSrc2 = Z + (size_t)(colBase + 64 + sr) * O_DIM + sg * 8;

    f32x4 acc[4][4] = {};

    GLOAD_LDS(aSrc,  base + tid * 8);
    GLOAD_LDS(aSrc2, base + (256 + tid) * 8);
    GLOAD_LDS(bSrc,  base + 4096 + tid * 8);
    GLOAD_LDS(bSrc2, base + 4096 + (256 + tid) * 8);
    __syncthreads();

    int cur = 0;
    for (int k0 = 0; k0 < O_DIM; k0 += 32) {
        if (k0 + 32 < O_DIM) {
            bf16_t* nA = base + (cur ^ 1) * 8192;
            GLOAD_LDS(aSrc  + k0 + 32, nA + tid * 8);
            GLOAD_LDS(aSrc2 + k0 + 32, nA + (256 + tid) * 8);
            GLOAD_LDS(bSrc  + k0 + 32, nA + 4096 + tid * 8);
            GLOAD_LDS(bSrc2 + k0 + 32, nA + 4096 + (256 + tid) * 8);
        }
        bf16_t* sA = base + cur * 8192;
        bf16_t* sB = sA + 4096;
        bf16x8 af[4], bfr[4];
#pragma unroll
        for (int i = 0; i < 4; ++i) {
            const int ra = wr + i * 16 + l15;
            const int rb = wc + i * 16 + l15;
            af[i]  = *(bf16x8*)&sA[ra * 32 + ((quad ^ ((ra >> 1) & 3)) << 3)];
            bfr[i] = *(bf16x8*)&sB[rb * 32 + ((quad ^ ((rb >> 1) & 3)) << 3)];
        }
#pragma unroll
        for (int i = 0; i < 4; ++i)
#pragma unroll
            for (int j = 0; j < 4; ++j)
                acc[i][j] = __builtin_amdgcn_mfma_f32_16x16x32_bf16(af[i], bfr[j], acc[i][j], 0, 0, 0);
        __syncthreads();
        cur ^= 1;
    }

    const int lrBase = (wave >> 1) * 16;
    for (int i = 0; i < 4; ++i) {
#pragma unroll
        for (int j = 0; j < 4; ++j)
#pragma unroll
            for (int r = 0; r < 4; ++r)
                sE[(lrBase + quad * 4 + r) * EP_STRIDE + wc + j * 16 + l15] = acc[i][j][r];
        __syncthreads();
#pragma unroll
        for (int p = 0; p < 4; ++p) {
            const int idx4 = p * 256 + tid;
            const int lr = idx4 >> 5;
            const int c4 = idx4 & 31;
            f32x4 v = *(f32x4*)&sE[lr * EP_STRIDE + c4 * 4];
            f32x4 o;
            o[0] = fsigmoid(v[0]); o[1] = fsigmoid(v[1]);
            o[2] = fsigmoid(v[2]); o[3] = fsigmoid(v[3]);
            const int grow = rowBase + (lr >> 4) * 64 + i * 16 + (lr & 15);
            *(f32x4*)&out[(size_t)grow * N_NODES + colBase + c4 * 4] = o;
        }
        __syncthreads();
    }
}

// ---------------- sparse attention (+ fused L2-norm on layer 1)
__global__ __launch_bounds__(256) void attn_k(const unsigned short* __restrict__ hb,
                                              const int* __restrict__ ecnt,
                                              const int* __restrict__ eidx,
                                              const float* __restrict__ Mm,
                                              const float* __restrict__ s_self4,
                                              const float* __restrict__ s_neigh4,
                                              unsigned short* __restrict__ out0,
                                              float* __restrict__ out1,
                                              unsigned short* __restrict__ zb,
                                              int layer) {
    const int n = blockIdx.x;
    const int tid = threadIdx.x;
    __shared__ int midx[MAXE];
    __shared__ float ev[MAXE][HEADS];
    __shared__ float red2[2][HO];
    __shared__ float ws2[4];
    const int c = ecnt[n];

    // phase 1: per-edge scores (leaky relu); M gathered directly
    if (tid < c) {
        const int m = eidx[(size_t)n * MAXE + tid];
        const float Mv = Mm[((size_t)n << 12) + m];
        midx[tid] = m;
        const float4 ss = *(const float4*)&s_self4[n * HEADS];
        const float4 sn = *(const float4*)&s_neigh4[m * HEADS];
        float e0 = (ss.x + sn.x) * Mv, e1 = (ss.y + sn.y) * Mv;
        float e2 = (ss.z + sn.z) * Mv, e3 = (ss.w + sn.w) * Mv;
        ev[tid][0] = e0 > 0.f ? e0 : LRELU_A * e0;
        ev[tid][1] = e1 > 0.f ? e1 : LRELU_A * e1;
        ev[tid][2] = e2 > 0.f ? e2 : LRELU_A * e2;
        ev[tid][3] = e3 > 0.f ? e3 : LRELU_A * e3;
    }
    __syncthreads();

    // phase 2: wave w = softmax over head w
    {
        const int w = tid >> 6, lane = tid & 63;
        float mx = -1e30f;
        for (int k = lane; k < c; k += 64) mx = fmaxf(mx, ev[k][w]);
        for (int off = 32; off; off >>= 1) mx = fmaxf(mx, __shfl_xor(mx, off, 64));
        float s = 0.f;
        for (int k = lane; k < c; k += 64) {
            float p = fexp(ev[k][w] - mx);
            ev[k][w] = p;
            s += p;
        }
        for (int off = 32; off; off >>= 1) s += __shfl_xor(s, off, 64);
        float inv = __builtin_amdgcn_rcpf(s);
        for (int k = lane; k < c; k += 64) ev[k][w] *= inv;
    }
    __syncthreads();

    // phase 3: gather-aggregate; halves process even/odd edges
    const int half = tid >> 7;
    const int t    = tid & 127;
    const int hh   = t >> 5;
    float acc[8] = {};
#pragma unroll 2
    for (int k = half; k < c; k += 2) {
        const int m = midx[k];
        const float w = ev[k][hh];
        const u16x8 hv = *(const u16x8*)&hb[(size_t)m * HO + t * 8];
#pragma unroll
        for (int j = 0; j < 8; ++j) acc[j] += w * b2f(hv[j]);
    }
#pragma unroll
    for (int j = 0; j < 8; ++j) red2[half][t * 8 + j] = acc[j];
    __syncthreads();

    if (layer == 0) {
        const int o = tid * 4;
        ushort4 ov;
        float v0 = red2[0][o + 0] + red2[1][o + 0];
        float v1 = red2[0][o + 1] + red2[1][o + 1];
        float v2 = red2[0][o + 2] + red2[1][o + 2];
        float v3 = red2[0][o + 3] + red2[1][o + 3];
        ov.x = f2b(v0 > 0.f ? v0 : fexp(v0) - 1.f);
        ov.y = f2b(v1 > 0.f ? v1 : fexp(v1) - 1.f);
        ov.z = f2b(v2 > 0.f ? v2 : fexp(v2) - 1.f);
        ov.w = f2b(v3 > 0.f ? v3 : fexp(v3) - 1.f);
        *(ushort4*)&out0[(size_t)n * HO + o] = ov;
    } else {
        // head-mean + fused row L2 normalize
        const int o = tid;
        float v = 0.f;
#pragma unroll
        for (int h = 0; h < HEADS; ++h)
            v += red2[0][h * O_DIM + o] + red2[1][h * O_DIM + o];
        v *= 0.25f;
        float p = v * v;
        for (int off = 32; off; off >>= 1) p += __shfl_down(p, off, 64);
        if ((tid & 63) == 0) ws2[tid >> 6] = p;
        __syncthreads();
        const float ssq = ws2[0] + ws2[1] + ws2[2] + ws2[3];
        const float denom = fmaxf(sqrtf(ssq), 1e-12f);
        const float zn = v / denom;
        out1[(size_t)n * O_DIM + o] = zn;
        zb[(size_t)n * O_DIM + o]   = f2b(zn);
    }
}

extern "C" void kernel_launch(void* const* d_in, const int* in_sizes, int n_in,
                              void* d_out, int out_size, void* d_ws, size_t ws_size,
                              hipStream_t stream) {
    const float* x   = (const float*)d_in[0];
    const float* adj = (const float*)d_in[1];
    const float* Mm  = (const float*)d_in[2];
    const float* W0  = (const float*)d_in[3];
    const float* as0 = (const float*)d_in[4];
    const float* an0 = (const float*)d_in[5];
    const float* W1  = (const float*)d_in[6];
    const float* as1 = (const float*)d_in[7];
    const float* an1 = (const float*)d_in[8];
    float* out = (float*)d_out;

    unsigned short* hb    = (unsigned short*)d_ws;        // [N][HO] bf16, 8 MB
    unsigned short* hin1b = hb + (size_t)N_NODES * HO;    // [N][HO] bf16, 8 MB
    unsigned short* xb    = hin1b + (size_t)N_NODES * HO; // [N][F] bf16, 4 MB
    unsigned short* wt0   = xb + (size_t)N_NODES * F_IN0; // 1 MB
    unsigned short* wt1   = wt0 + HEADS * O_DIM * F_IN0;  // 2 MB
    unsigned short* zb    = wt1 + HEADS * O_DIM * HO;     // [N][O] bf16, 2 MB
    float* s0s = (float*)(zb + (size_t)N_NODES * O_DIM);  // 4 score bufs, 64 KB each
    float* s0n = s0s + (size_t)N_NODES * HEADS;
    float* s1s = s0n + (size_t)N_NODES * HEADS;
    float* s1n = s1s + (size_t)N_NODES * HEADS;
    int*   eidx = (int*)(s1n + (size_t)N_NODES * HEADS);
    int*   ecnt = eidx + (size_t)N_NODES * MAXE;
    float* zbuf = out + (size_t)N_NODES * N_NODES;  // z fp32 in d_out tail

    // fused prep: conversions | transposes | edges | zero score bufs (s0s..s1n contiguous)
    prep_k<<<4608, 256, 0, stream>>>(x, W0, W1, adj, xb, wt0, wt1, ecnt, eidx, s0s);

    // layer 0: GEMM + fused scores
    mfma_nt<<<dim3(64, 4, 4), 256, 0, stream>>>((const bf16_t*)xb, (const bf16_t*)wt0, hb,
                                                as0, an0, s0s, s0n,
                                                F_IN0, HO,
                                                (unsigned long long)O_DIM * F_IN0,
                                                (unsigned long long)O_DIM);
    attn_k<<<N_NODES, 256, 0, stream>>>(hb, ecnt, eidx, Mm, s0s, s0n, hin1b, nullptr, nullptr, 0);

    // layer 1: GEMM + fused scores; attn + fused norm
    mfma_nt<<<dim3(64, 4, 4), 256, 0, stream>>>((const bf16_t*)hin1b, (const bf16_t*)wt1, hb,
                                                as1, an1, s1s, s1n,
                                                HO, HO,
                                                (unsigned long long)O_DIM * HO,
                                                (unsigned long long)O_DIM);
    attn_k<<<N_NODES, 256, 0, stream>>>(hb, ecnt, eidx, Mm, s1s, s1n, nullptr, zbuf, zb, 1);

    // decode
    decode_k<<<dim3(32, 32), 256, 0, stream>>>((const bf16_t*)zb, out);
}